// Round 4
// baseline (1643.976 us; speedup 1.0000x reference)
//
#include <hip/hip_runtime.h>
#include <math.h>

// LADMM unrolled network, MI355X — Woodbury operator form, LDS-free,
// DS-pipe-minimized. x_new = xc - (A xc) @ H, xc = Cinv y (C circulant).
// Cinv via exact bidirectional exponential IIR (c_d = K*rho^|d|) with
// weighted wave scans. Cross-lane ops use DPP row_ror / wave_shr /
// permlane32_swap (VALU pipe) instead of ds_bpermute wherever possible:
// per-layer DS ops drop ~148 -> 30 vs the r2 LDS kernel.
#define NS 300
#define NM 9
#define NB 131072
#define NL 5

// workspace layout (floats)
#define OFF_C 0        // [NL][NS]     circulant kernel of C^-1 (setup only)
#define OFF_G 1536     // [NL][NM][NS] G = A C^-1 (setup only, feeds k_SH)
#define OFF_H 15360    // [NL][NM][NS] H = S^-1 G

typedef int int2_t __attribute__((ext_vector_type(2)));

// DPP move: 0x121/0x122/0x124/0x128 = row_ror:1/2/4/8,
// 0x130 = wave_shl:1 (lane i <- i+1, lane63 -> 0 w/ bound_ctrl),
// 0x138 = wave_shr:1 (lane i <- i-1, lane0  -> 0 w/ bound_ctrl).
template <int CTRL>
__device__ __forceinline__ float dppf(float v) {
  return __int_as_float(__builtin_amdgcn_update_dpp(
      0, __float_as_int(v), CTRL, 0xF, 0xF, true));
}

__device__ __forceinline__ float readlanef(float v, int lane) {
  return __int_as_float(__builtin_amdgcn_readlane(__float_as_int(v), lane));
}

// full 64-lane sum, result on every lane; 1 ds_swizzle + 1 permlane,
// rest VALU (DPP rotation reduce within 16-lane rows).
__device__ __forceinline__ float wsum64(float v) {
  v += dppf<0x128>(v);   // + rotate-by-8 within row
  v += dppf<0x124>(v);   // + rotate-by-4
  v += dppf<0x122>(v);   // + rotate-by-2
  v += dppf<0x121>(v);   // + rotate-by-1  -> row sums
  v += __int_as_float(__builtin_amdgcn_ds_swizzle(__float_as_int(v), 0x401F)); // xor 16
  int2_t pr = __builtin_amdgcn_permlane32_swap(
      __float_as_int(v), __float_as_int(v), false, false);
  return __int_as_float(pr.x) + __int_as_float(pr.y);  // pr.x=v[l&31], pr.y=v[l|32]
}

// ---------------- setup 1: first column of C^-1 per layer (DFT) ----------
__global__ void k_cinv(const float* __restrict__ alpha,
                       const float* __restrict__ gamma,
                       float* __restrict__ cbuf) {
  __shared__ double costab[NS];
  __shared__ double invlam[NS];
  const int l = blockIdx.x;
  const int j = threadIdx.x;
  const double al = (double)alpha[l], g = (double)gamma[l];
  const double tpn = 6.283185307179586476925286766559 / (double)NS;
  if (j < NS) {
    double cj = cos(tpn * (double)j);
    costab[j] = cj;
    invlam[j] = 1.0 / (al + 2.0 * g * (1.0 - cj));
  }
  __syncthreads();
  if (j < NS) {
    double s = 0.0;
    for (int m = 0; m < NS; ++m) s += costab[(j * m) % NS] * invlam[m];
    cbuf[l * NS + j] = (float)(s / (double)NS);
  }
}

// ---------------- setup 2: G[l][k][j] = sum_i A[k][i] * c[(i-j) mod NS] ---
__global__ void k_G(const float* __restrict__ A, const float* __restrict__ cbuf,
                    float* __restrict__ Gbuf) {
  const int l = blockIdx.x / NM, kk = blockIdx.x % NM;
  const int j = threadIdx.x;
  if (j >= NS) return;
  const float* c = cbuf + l * NS;
  const float* Ak = A + kk * NS;
  float s = 0.f;
  for (int i = 0; i < NS; ++i) {
    int d = i - j; if (d < 0) d += NS;
    s = fmaf(Ak[i], c[d], s);
  }
  Gbuf[(l * NM + kk) * NS + j] = s;
}

// ---------------- setup 3: S = I + G A^T ; invert 9x9 ; H = S^-1 G -------
__global__ void k_SH(const float* __restrict__ A, const float* __restrict__ Gbuf,
                     float* __restrict__ Hbuf) {
  __shared__ float Si[9][18];
  const int l = blockIdx.x, t = threadIdx.x;
  const float* G = Gbuf + l * NM * NS;
  if (t < 81) {
    int p = t / 9, q = t % 9;
    float s = (p == q) ? 1.f : 0.f;
    const float* Gp = G + p * NS;
    const float* Aq = A + q * NS;
    for (int j = 0; j < NS; ++j) s = fmaf(Gp[j], Aq[j], s);
    Si[p][q] = s;
    Si[p][q + 9] = (p == q) ? 1.f : 0.f;
  }
  __syncthreads();
  if (t == 0) {
    for (int p = 0; p < 9; ++p) {
      float piv = 1.f / Si[p][p];
      for (int q = 0; q < 18; ++q) Si[p][q] *= piv;
      for (int r = 0; r < 9; ++r) if (r != p) {
        float f = Si[r][p];
        for (int q = 0; q < 18; ++q) Si[r][q] -= f * Si[p][q];
      }
    }
  }
  __syncthreads();
  for (int idx = t; idx < NM * NS; idx += blockDim.x) {
    int p = idx / NS, j = idx % NS;
    float s = 0.f;
    #pragma unroll
    for (int q = 0; q < 9; ++q) s = fmaf(Si[p][q + 9], G[q * NS + j], s);
    Hbuf[l * NM * NS + idx] = s;
  }
}

// ---------------- main fused kernel: 8 rows/block, LDS-free ---------------
// launch_bounds(256,4): proven no-spill config (r2: VGPR 64, clean HBM
// traffic). (256,5) spilled catastrophically (r1); r3's extra liveness at
// the same 64-VGPR budget spilled ~170B/thread -> this version trims peak
// liveness (s-substitution kills y after scans; corrections in place).
__global__ __launch_bounds__(256, 4)
void k_main(const float* __restrict__ b, const float* __restrict__ A,
            const float* __restrict__ gam, const float* __restrict__ lamv,
            const float* __restrict__ alp,
            const float* __restrict__ Hbuf, float* __restrict__ out) {
  const int tid = threadIdx.x;
  const int tx = tid & 63;
  const int wv = tid >> 6;              // wave 0..3, owns rows 2*wv..2*wv+1
  const int col = tx * 5;
  const bool live = (tx < 60);
  const int colc = live ? col : 0;      // clamped col for global A/H reads
  const int row0 = blockIdx.x * 8 + wv * 2;

  // persistent per-row state
  float x[2][5], eta[2][5], tau[2][5], bA[2][5];
  #pragma unroll
  for (int r = 0; r < 2; ++r)
    #pragma unroll
    for (int c = 0; c < 5; ++c) { x[r][c] = 1.f; eta[r][c] = 0.f; tau[r][c] = 0.f; bA[r][c] = 0.f; }

  // bA = b @ A (constant across layers)
  #pragma unroll
  for (int r = 0; r < 2; ++r) {
    float bb0[NM];
    #pragma unroll
    for (int k = 0; k < NM; ++k) bb0[k] = b[(size_t)(row0 + r) * NM + k];
    if (live) {
      #pragma unroll
      for (int c = 0; c < 5; ++c) {
        float s = 0.f;
        #pragma unroll
        for (int k = 0; k < NM; ++k) s = fmaf(bb0[k], A[k * NS + col + c], s);
        bA[r][c] = s;
      }
    }
  }

  for (int l = 0; l < NL; ++l) {
    const float g = gam[l], lm = lamv[l], al = alp[l];
    const float ig = 1.f / g, ia = 1.f / al, thr = lm * ig;
    // analytic Cinv kernel: c_d = Kc * rho^|d|
    const float m2 = al + 2.f * g;
    const float disc = sqrtf(fmaxf(fmaf(m2, m2, -4.f * g * g), 0.f));
    float rho = (m2 - disc) / (2.f * g);
    rho = fmaxf(rho, 1e-30f);                 // guard log2f(0)
    const float Kc = 1.f / disc;
    const float rp2 = rho * rho, rp3 = rp2 * rho, rp4 = rp2 * rp2, rp5 = rp4 * rho;
    const float l2r = log2f(rho);
    const float rcf = exp2f((float)col * l2r);          // rho^col
    const float rcb = exp2f((float)(295 - col) * l2r);  // rho^(295-col)
    const float* Hg = Hbuf + l * NM * NS;

    float y[2][5], z[2][5], sres[2][5], xc[2][5];

    // Phase A: u, w, residual y; z = eta - g*u ; sres = bA - y - z
    #pragma unroll
    for (int r = 0; r < 2; ++r) {
      float x4 = x[r][4];
      float xps = dppf<0x138>(x4);                       // lane i <- i-1
      float xp = (tx == 0) ? readlanef(x4, 59) : xps;    // circular prevlane
      #pragma unroll
      for (int c = 0; c < 5; ++c) {
        float xl = (c == 0) ? xp : x[r][c - 1];
        float v = (xl - x[r][c]) + eta[r][c] * ig;
        float av = fabsf(v) - thr;
        float uu = (av > 0.f) ? copysignf(av, v) : 0.f;
        float ww = fmaf(tau[r][c], ia, x[r][c]);
        ww = (ww > 0.f) ? ww : 0.f;
        float yv = bA[r][c] + al * ww - tau[r][c] + g * uu - eta[r][c];
        y[r][c] = live ? yv : 0.f;           // dead lanes MUST be 0 for scans
        z[r][c] = fmaf(-g, uu, eta[r][c]);   // z = eta - g*u
        sres[r][c] = (bA[r][c] - y[r][c]) - z[r][c];
      }
    }

    // xc = Kc * (f + b - y): bidirectional exponential IIR via wave scans.
    // Fold levels d<=8 (residual weight rho^40 ~ 2e-17, below fp32 ULP).
    #pragma unroll
    for (int r = 0; r < 2; ++r) {
      // forward f[j] = y[j] + rho*f[j-1]
      float f0 = y[r][0];
      float f1 = fmaf(rho, f0, y[r][1]);
      float f2 = fmaf(rho, f1, y[r][2]);
      float f3 = fmaf(rho, f2, y[r][3]);
      float f4 = fmaf(rho, f3, y[r][4]);
      float cf = f4;
      cf = fmaf(rp5, dppf<0x138>(cf), cf);               // d=1 (zero-fill)
      float rw = rp5 * rp5;
      float tt = __shfl_up(cf, 2, 64);
      cf = fmaf((tx >= 2) ? rw : 0.f, tt, cf); rw *= rw;
      tt = __shfl_up(cf, 4, 64);
      cf = fmaf((tx >= 4) ? rw : 0.f, tt, cf); rw *= rw;
      tt = __shfl_up(cf, 8, 64);
      cf = fmaf((tx >= 8) ? rw : 0.f, tt, cf);
      float Ef = dppf<0x138>(cf);                        // excl carry, lane0=0
      Ef = fmaf(rcf, readlanef(cf, 59), Ef);             // circular wrap

      // backward b[j] = y[j] + rho*b[j+1]
      float g4 = y[r][4];
      float g3 = fmaf(rho, g4, y[r][3]);
      float g2 = fmaf(rho, g3, y[r][2]);
      float g1 = fmaf(rho, g2, y[r][1]);
      float g0 = fmaf(rho, g1, y[r][0]);
      float cb = g0;
      cb = fmaf(rp5, dppf<0x130>(cb), cb);               // d=1 (zero-fill)
      rw = rp5 * rp5;
      tt = __shfl_down(cb, 2, 64);
      cb = fmaf((tx <= 61) ? rw : 0.f, tt, cb); rw *= rw;
      tt = __shfl_down(cb, 4, 64);
      cb = fmaf((tx <= 59) ? rw : 0.f, tt, cb); rw *= rw;
      tt = __shfl_down(cb, 8, 64);
      cb = fmaf((tx <= 55) ? rw : 0.f, tt, cb);
      float Eb = dppf<0x130>(cb);                        // excl carry, lane63=0
      Eb = fmaf(rcb, readlanef(cb, 0), Eb);              // circular wrap

      // fixups: f[c] += rho^(c+1)*Ef ; b[c] += rho^(5-c)*Eb
      f0 = fmaf(rho, Ef, f0);  g0 = fmaf(rp5, Eb, g0);
      f1 = fmaf(rp2, Ef, f1);  g1 = fmaf(rp4, Eb, g1);
      f2 = fmaf(rp3, Ef, f2);  g2 = fmaf(rp3, Eb, g2);
      f3 = fmaf(rp4, Ef, f3);  g3 = fmaf(rp2, Eb, g3);
      f4 = fmaf(rp5, Ef, f4);  g4 = fmaf(rho, Eb, g4);

      // mask dead lanes: xc feeds the A-dot partials, must be exact zero
      xc[r][0] = live ? (Kc * ((f0 + g0) - y[r][0])) : 0.f;
      xc[r][1] = live ? (Kc * ((f1 + g1) - y[r][1])) : 0.f;
      xc[r][2] = live ? (Kc * ((f2 + g2) - y[r][2])) : 0.f;
      xc[r][3] = live ? (Kc * ((f3 + g3) - y[r][3])) : 0.f;
      xc[r][4] = live ? (Kc * ((f4 + g4) - y[r][4])) : 0.f;
    }
    // y dead from here (folded into sres)

    // t[r][q] = A[q].xc[r]  (identity: y.G[q] = A[q].(Cinv y))
    float p[2][NM];
    #pragma unroll
    for (int q = 0; q < NM; ++q) { p[0][q] = 0.f; p[1][q] = 0.f; }
    #pragma unroll
    for (int q = 0; q < NM; ++q) {
      #pragma unroll
      for (int c = 0; c < 5; ++c) {
        float a = A[q * NS + colc + c];
        p[0][q] = fmaf(xc[0][c], a, p[0][q]);
        p[1][q] = fmaf(xc[1][c], a, p[1][q]);
      }
    }
    #pragma unroll
    for (int q = 0; q < NM; ++q) {
      p[0][q] = wsum64(p[0][q]);
      p[1][q] = wsum64(p[1][q]);
    }

    // correction in place: xc -= t[q] * H[q]
    #pragma unroll
    for (int q = 0; q < NM; ++q) {
      #pragma unroll
      for (int c = 0; c < 5; ++c) {
        float h = Hg[q * NS + colc + c];
        xc[0][c] = fmaf(-p[0][q], h, xc[0][c]);
        xc[1][c] = fmaf(-p[1][q], h, xc[1][c]);
      }
    }

    // x = xc; dual updates: eta' = g*(xl'-x') + z ; tau' = al*x' + sres
    #pragma unroll
    for (int r = 0; r < 2; ++r) {
      #pragma unroll
      for (int c = 0; c < 5; ++c) x[r][c] = xc[r][c];
      float x4 = x[r][4];
      float xps = dppf<0x138>(x4);
      float xp = (tx == 0) ? readlanef(x4, 59) : xps;
      #pragma unroll
      for (int c = 0; c < 5; ++c) {
        float xl = (c == 0) ? xp : x[r][c - 1];
        eta[r][c] = fmaf(g, xl - x[r][c], z[r][c]);
        tau[r][c] = fmaf(al, x[r][c], sres[r][c]);
      }
    }
  }

  if (live) {
    #pragma unroll
    for (int r = 0; r < 2; ++r) {
      size_t o = (size_t)(row0 + r) * NS + col;
      #pragma unroll
      for (int c = 0; c < 5; ++c) out[o + c] = x[r][c];
    }
  }
}

extern "C" void kernel_launch(void* const* d_in, const int* in_sizes, int n_in,
                              void* d_out, int out_size, void* d_ws, size_t ws_size,
                              hipStream_t stream) {
  const float* b   = (const float*)d_in[0];
  const float* A   = (const float*)d_in[2];
  const float* gam = (const float*)d_in[3];
  const float* lm  = (const float*)d_in[4];
  const float* al  = (const float*)d_in[5];
  float* out = (float*)d_out;
  float* ws  = (float*)d_ws;

  float* cbuf = ws + OFF_C;
  float* Gbuf = ws + OFF_G;
  float* Hbuf = ws + OFF_H;

  k_cinv<<<dim3(NL), dim3(320), 0, stream>>>(al, gam, cbuf);
  k_G   <<<dim3(NL * NM), dim3(320), 0, stream>>>(A, cbuf, Gbuf);
  k_SH  <<<dim3(NL), dim3(128), 0, stream>>>(A, Gbuf, Hbuf);
  k_main<<<dim3(NB / 8), dim3(256), 0, stream>>>(b, A, gam, lm, al,
                                                 Hbuf, out);
}

// Round 5
// 776.145 us; speedup vs baseline: 2.1181x; 2.1181x over previous
//
#include <hip/hip_runtime.h>
#include <math.h>

// LADMM unrolled network, MI355X — Woodbury operator form, LDS-free,
// DS-pipe-minimized. x_new = xc - (A xc) @ H, xc = Cinv y (C circulant).
// Cinv via exact bidirectional exponential IIR (c_d = K*rho^|d|) with
// weighted wave scans. Cross-lane ops use DPP row_ror / wave_shr /
// permlane32_swap (VALU pipe) instead of ds_bpermute wherever possible.
//
// Register discipline (hard-learned): the backend's occupancy heuristic
// with __launch_bounds__(256,N) pins VGPRs at 512/(rounded waves) and
// SPILLS to scratch rather than allocating more (r1: 1.1 GB, r3: 0.7 GB,
// r4: 4.3 GB spill traffic). amdgpu_waves_per_eu(3,4) sets budget ~168
// (min=3) and forbids chasing 8 waves (max=4) -> no spill cliff.
#define NS 300
#define NM 9
#define NB 131072
#define NL 5

// workspace layout (floats)
#define OFF_C 0        // [NL][NS]     circulant kernel of C^-1 (setup only)
#define OFF_G 1536     // [NL][NM][NS] G = A C^-1 (setup only, feeds k_SH)
#define OFF_H 15360    // [NL][NM][NS] H = S^-1 G

typedef int int2_t __attribute__((ext_vector_type(2)));

// DPP move: 0x121/0x122/0x124/0x128 = row_ror:1/2/4/8,
// 0x130 = wave_shl:1 (lane i <- i+1, lane63 -> 0 w/ bound_ctrl),
// 0x138 = wave_shr:1 (lane i <- i-1, lane0  -> 0 w/ bound_ctrl).
template <int CTRL>
__device__ __forceinline__ float dppf(float v) {
  return __int_as_float(__builtin_amdgcn_update_dpp(
      0, __float_as_int(v), CTRL, 0xF, 0xF, true));
}

__device__ __forceinline__ float readlanef(float v, int lane) {
  return __int_as_float(__builtin_amdgcn_readlane(__float_as_int(v), lane));
}

// full 64-lane sum, result on every lane; 1 ds_swizzle + 1 permlane,
// rest VALU (DPP rotation reduce within 16-lane rows). Verified r4.
__device__ __forceinline__ float wsum64(float v) {
  v += dppf<0x128>(v);   // + rotate-by-8 within row
  v += dppf<0x124>(v);   // + rotate-by-4
  v += dppf<0x122>(v);   // + rotate-by-2
  v += dppf<0x121>(v);   // + rotate-by-1  -> row sums
  v += __int_as_float(__builtin_amdgcn_ds_swizzle(__float_as_int(v), 0x401F)); // xor 16
  int2_t pr = __builtin_amdgcn_permlane32_swap(
      __float_as_int(v), __float_as_int(v), false, false);
  return __int_as_float(pr.x) + __int_as_float(pr.y);
}

// ---------------- setup 1: first column of C^-1 per layer (DFT) ----------
__global__ void k_cinv(const float* __restrict__ alpha,
                       const float* __restrict__ gamma,
                       float* __restrict__ cbuf) {
  __shared__ double costab[NS];
  __shared__ double invlam[NS];
  const int l = blockIdx.x;
  const int j = threadIdx.x;
  const double al = (double)alpha[l], g = (double)gamma[l];
  const double tpn = 6.283185307179586476925286766559 / (double)NS;
  if (j < NS) {
    double cj = cos(tpn * (double)j);
    costab[j] = cj;
    invlam[j] = 1.0 / (al + 2.0 * g * (1.0 - cj));
  }
  __syncthreads();
  if (j < NS) {
    double s = 0.0;
    for (int m = 0; m < NS; ++m) s += costab[(j * m) % NS] * invlam[m];
    cbuf[l * NS + j] = (float)(s / (double)NS);
  }
}

// ---------------- setup 2: G[l][k][j] = sum_i A[k][i] * c[(i-j) mod NS] ---
__global__ void k_G(const float* __restrict__ A, const float* __restrict__ cbuf,
                    float* __restrict__ Gbuf) {
  const int l = blockIdx.x / NM, kk = blockIdx.x % NM;
  const int j = threadIdx.x;
  if (j >= NS) return;
  const float* c = cbuf + l * NS;
  const float* Ak = A + kk * NS;
  float s = 0.f;
  for (int i = 0; i < NS; ++i) {
    int d = i - j; if (d < 0) d += NS;
    s = fmaf(Ak[i], c[d], s);
  }
  Gbuf[(l * NM + kk) * NS + j] = s;
}

// ---------------- setup 3: S = I + G A^T ; invert 9x9 ; H = S^-1 G -------
__global__ void k_SH(const float* __restrict__ A, const float* __restrict__ Gbuf,
                     float* __restrict__ Hbuf) {
  __shared__ float Si[9][18];
  const int l = blockIdx.x, t = threadIdx.x;
  const float* G = Gbuf + l * NM * NS;
  if (t < 81) {
    int p = t / 9, q = t % 9;
    float s = (p == q) ? 1.f : 0.f;
    const float* Gp = G + p * NS;
    const float* Aq = A + q * NS;
    for (int j = 0; j < NS; ++j) s = fmaf(Gp[j], Aq[j], s);
    Si[p][q] = s;
    Si[p][q + 9] = (p == q) ? 1.f : 0.f;
  }
  __syncthreads();
  if (t == 0) {
    for (int p = 0; p < 9; ++p) {
      float piv = 1.f / Si[p][p];
      for (int q = 0; q < 18; ++q) Si[p][q] *= piv;
      for (int r = 0; r < 9; ++r) if (r != p) {
        float f = Si[r][p];
        for (int q = 0; q < 18; ++q) Si[r][q] -= f * Si[p][q];
      }
    }
  }
  __syncthreads();
  for (int idx = t; idx < NM * NS; idx += blockDim.x) {
    int p = idx / NS, j = idx % NS;
    float s = 0.f;
    #pragma unroll
    for (int q = 0; q < 9; ++q) s = fmaf(Si[p][q + 9], G[q * NS + j], s);
    Hbuf[l * NM * NS + idx] = s;
  }
}

// ---------------- main fused kernel: 8 rows/block, LDS-free ---------------
__global__ __launch_bounds__(256)
__attribute__((amdgpu_waves_per_eu(3, 4)))
void k_main(const float* __restrict__ b, const float* __restrict__ A,
            const float* __restrict__ gam, const float* __restrict__ lamv,
            const float* __restrict__ alp,
            const float* __restrict__ Hbuf, float* __restrict__ out) {
  const int tid = threadIdx.x;
  const int tx = tid & 63;
  const int wv = tid >> 6;              // wave 0..3, owns rows 2*wv..2*wv+1
  const int col = tx * 5;
  const bool live = (tx < 60);
  const int colc = live ? col : 0;      // clamped col for global A/H reads
  const int row0 = blockIdx.x * 8 + wv * 2;

  // persistent per-row state
  float x[2][5], eta[2][5], tau[2][5], bA[2][5];
  #pragma unroll
  for (int r = 0; r < 2; ++r)
    #pragma unroll
    for (int c = 0; c < 5; ++c) { x[r][c] = 1.f; eta[r][c] = 0.f; tau[r][c] = 0.f; bA[r][c] = 0.f; }

  // bA = b @ A (constant across layers)
  #pragma unroll
  for (int r = 0; r < 2; ++r) {
    float bb0[NM];
    #pragma unroll
    for (int k = 0; k < NM; ++k) bb0[k] = b[(size_t)(row0 + r) * NM + k];
    if (live) {
      #pragma unroll
      for (int c = 0; c < 5; ++c) {
        float s = 0.f;
        #pragma unroll
        for (int k = 0; k < NM; ++k) s = fmaf(bb0[k], A[k * NS + col + c], s);
        bA[r][c] = s;
      }
    }
  }

  for (int l = 0; l < NL; ++l) {
    const float g = gam[l], lm = lamv[l], al = alp[l];
    const float ig = 1.f / g, ia = 1.f / al, thr = lm * ig;
    // analytic Cinv kernel: c_d = Kc * rho^|d|
    const float m2 = al + 2.f * g;
    const float disc = sqrtf(fmaxf(fmaf(m2, m2, -4.f * g * g), 0.f));
    float rho = (m2 - disc) / (2.f * g);
    rho = fmaxf(rho, 1e-30f);                 // guard log2f(0)
    const float Kc = 1.f / disc;
    const float rp2 = rho * rho, rp3 = rp2 * rho, rp4 = rp2 * rp2, rp5 = rp4 * rho;
    const float l2r = log2f(rho);
    const float rcf = exp2f((float)col * l2r);          // rho^col
    const float rcb = exp2f((float)(295 - col) * l2r);  // rho^(295-col)
    const float* Hg = Hbuf + l * NM * NS;

    float y[2][5], z[2][5], sres[2][5], xc[2][5];

    // Phase A: u, w, residual y; z = eta - g*u ; sres = bA - y - z
    #pragma unroll
    for (int r = 0; r < 2; ++r) {
      float x4 = x[r][4];
      float xps = dppf<0x138>(x4);                       // lane i <- i-1
      float xp = (tx == 0) ? readlanef(x4, 59) : xps;    // circular prevlane
      #pragma unroll
      for (int c = 0; c < 5; ++c) {
        float xl = (c == 0) ? xp : x[r][c - 1];
        float v = (xl - x[r][c]) + eta[r][c] * ig;
        float av = fabsf(v) - thr;
        float uu = (av > 0.f) ? copysignf(av, v) : 0.f;
        float ww = fmaf(tau[r][c], ia, x[r][c]);
        ww = (ww > 0.f) ? ww : 0.f;
        float yv = bA[r][c] + al * ww - tau[r][c] + g * uu - eta[r][c];
        y[r][c] = live ? yv : 0.f;           // dead lanes MUST be 0 for scans
        z[r][c] = fmaf(-g, uu, eta[r][c]);   // z = eta - g*u
        sres[r][c] = (bA[r][c] - y[r][c]) - z[r][c];
      }
    }

    // xc = Kc * (f + b - y): bidirectional exponential IIR via wave scans.
    // Fold levels d<=8 (residual weight rho^40 ~ 2e-17, below fp32 ULP).
    #pragma unroll
    for (int r = 0; r < 2; ++r) {
      // forward f[j] = y[j] + rho*f[j-1]
      float f0 = y[r][0];
      float f1 = fmaf(rho, f0, y[r][1]);
      float f2 = fmaf(rho, f1, y[r][2]);
      float f3 = fmaf(rho, f2, y[r][3]);
      float f4 = fmaf(rho, f3, y[r][4]);
      float cf = f4;
      cf = fmaf(rp5, dppf<0x138>(cf), cf);               // d=1 (zero-fill)
      float rw = rp5 * rp5;
      float tt = __shfl_up(cf, 2, 64);
      cf = fmaf((tx >= 2) ? rw : 0.f, tt, cf); rw *= rw;
      tt = __shfl_up(cf, 4, 64);
      cf = fmaf((tx >= 4) ? rw : 0.f, tt, cf); rw *= rw;
      tt = __shfl_up(cf, 8, 64);
      cf = fmaf((tx >= 8) ? rw : 0.f, tt, cf);
      float Ef = dppf<0x138>(cf);                        // excl carry, lane0=0
      Ef = fmaf(rcf, readlanef(cf, 59), Ef);             // circular wrap

      // backward b[j] = y[j] + rho*b[j+1]
      float g4 = y[r][4];
      float g3 = fmaf(rho, g4, y[r][3]);
      float g2 = fmaf(rho, g3, y[r][2]);
      float g1 = fmaf(rho, g2, y[r][1]);
      float g0 = fmaf(rho, g1, y[r][0]);
      float cb = g0;
      cb = fmaf(rp5, dppf<0x130>(cb), cb);               // d=1 (zero-fill)
      rw = rp5 * rp5;
      tt = __shfl_down(cb, 2, 64);
      cb = fmaf((tx <= 61) ? rw : 0.f, tt, cb); rw *= rw;
      tt = __shfl_down(cb, 4, 64);
      cb = fmaf((tx <= 59) ? rw : 0.f, tt, cb); rw *= rw;
      tt = __shfl_down(cb, 8, 64);
      cb = fmaf((tx <= 55) ? rw : 0.f, tt, cb);
      float Eb = dppf<0x130>(cb);                        // excl carry, lane63=0
      Eb = fmaf(rcb, readlanef(cb, 0), Eb);              // circular wrap

      // fixups: f[c] += rho^(c+1)*Ef ; b[c] += rho^(5-c)*Eb
      f0 = fmaf(rho, Ef, f0);  g0 = fmaf(rp5, Eb, g0);
      f1 = fmaf(rp2, Ef, f1);  g1 = fmaf(rp4, Eb, g1);
      f2 = fmaf(rp3, Ef, f2);  g2 = fmaf(rp3, Eb, g2);
      f3 = fmaf(rp4, Ef, f3);  g3 = fmaf(rp2, Eb, g3);
      f4 = fmaf(rp5, Ef, f4);  g4 = fmaf(rho, Eb, g4);

      // mask dead lanes: xc feeds the A-dot partials, must be exact zero
      xc[r][0] = live ? (Kc * ((f0 + g0) - y[r][0])) : 0.f;
      xc[r][1] = live ? (Kc * ((f1 + g1) - y[r][1])) : 0.f;
      xc[r][2] = live ? (Kc * ((f2 + g2) - y[r][2])) : 0.f;
      xc[r][3] = live ? (Kc * ((f3 + g3) - y[r][3])) : 0.f;
      xc[r][4] = live ? (Kc * ((f4 + g4) - y[r][4])) : 0.f;
    }
    // y dead from here (folded into sres)

    // Woodbury: xnew = xc - (A[q].xc) * H[q], q in groups of 3 to bound
    // partial-sum liveness at 6 (r4's all-18-at-once was the spill source).
    // xc must stay unmodified as the dot input -> corrections go to xnew.
    float xnew[2][5];
    #pragma unroll
    for (int r = 0; r < 2; ++r)
      #pragma unroll
      for (int c = 0; c < 5; ++c) xnew[r][c] = xc[r][c];

    #pragma unroll
    for (int qg = 0; qg < NM; qg += 3) {
      float p00 = 0.f, p01 = 0.f, p02 = 0.f, p10 = 0.f, p11 = 0.f, p12 = 0.f;
      #pragma unroll
      for (int c = 0; c < 5; ++c) {
        float a0 = A[(qg + 0) * NS + colc + c];
        float a1 = A[(qg + 1) * NS + colc + c];
        float a2 = A[(qg + 2) * NS + colc + c];
        p00 = fmaf(xc[0][c], a0, p00); p10 = fmaf(xc[1][c], a0, p10);
        p01 = fmaf(xc[0][c], a1, p01); p11 = fmaf(xc[1][c], a1, p11);
        p02 = fmaf(xc[0][c], a2, p02); p12 = fmaf(xc[1][c], a2, p12);
      }
      p00 = wsum64(p00); p01 = wsum64(p01); p02 = wsum64(p02);
      p10 = wsum64(p10); p11 = wsum64(p11); p12 = wsum64(p12);
      #pragma unroll
      for (int c = 0; c < 5; ++c) {
        float h0 = Hg[(qg + 0) * NS + colc + c];
        float h1 = Hg[(qg + 1) * NS + colc + c];
        float h2 = Hg[(qg + 2) * NS + colc + c];
        xnew[0][c] = fmaf(-p00, h0, xnew[0][c]);
        xnew[1][c] = fmaf(-p10, h0, xnew[1][c]);
        xnew[0][c] = fmaf(-p01, h1, xnew[0][c]);
        xnew[1][c] = fmaf(-p11, h1, xnew[1][c]);
        xnew[0][c] = fmaf(-p02, h2, xnew[0][c]);
        xnew[1][c] = fmaf(-p12, h2, xnew[1][c]);
      }
    }

    // x = xnew; dual updates: eta' = g*(xl'-x') + z ; tau' = al*x' + sres
    #pragma unroll
    for (int r = 0; r < 2; ++r) {
      #pragma unroll
      for (int c = 0; c < 5; ++c) x[r][c] = xnew[r][c];
      float x4 = x[r][4];
      float xps = dppf<0x138>(x4);
      float xp = (tx == 0) ? readlanef(x4, 59) : xps;
      #pragma unroll
      for (int c = 0; c < 5; ++c) {
        float xl = (c == 0) ? xp : x[r][c - 1];
        eta[r][c] = fmaf(g, xl - x[r][c], z[r][c]);
        tau[r][c] = fmaf(al, x[r][c], sres[r][c]);
      }
    }
  }

  if (live) {
    #pragma unroll
    for (int r = 0; r < 2; ++r) {
      size_t o = (size_t)(row0 + r) * NS + col;
      #pragma unroll
      for (int c = 0; c < 5; ++c) out[o + c] = x[r][c];
    }
  }
}

extern "C" void kernel_launch(void* const* d_in, const int* in_sizes, int n_in,
                              void* d_out, int out_size, void* d_ws, size_t ws_size,
                              hipStream_t stream) {
  const float* b   = (const float*)d_in[0];
  const float* A   = (const float*)d_in[2];
  const float* gam = (const float*)d_in[3];
  const float* lm  = (const float*)d_in[4];
  const float* al  = (const float*)d_in[5];
  float* out = (float*)d_out;
  float* ws  = (float*)d_ws;

  float* cbuf = ws + OFF_C;
  float* Gbuf = ws + OFF_G;
  float* Hbuf = ws + OFF_H;

  k_cinv<<<dim3(NL), dim3(320), 0, stream>>>(al, gam, cbuf);
  k_G   <<<dim3(NL * NM), dim3(320), 0, stream>>>(A, cbuf, Gbuf);
  k_SH  <<<dim3(NL), dim3(128), 0, stream>>>(A, Gbuf, Hbuf);
  k_main<<<dim3(NB / 8), dim3(256), 0, stream>>>(b, A, gam, lm, al,
                                                 Hbuf, out);
}